// Round 1
// baseline (158.449 us; speedup 1.0000x reference)
//
#include <hip/hip_runtime.h>
#include <math.h>

#define B_N 8192
#define D_N 512
#define S_N 5
#define C_N 2048
#define H_N 4

typedef __attribute__((ext_vector_type(8))) short bf16x8;
typedef __attribute__((ext_vector_type(4))) float floatx4;

__device__ __forceinline__ float bf2f(short u) {
  union { unsigned int i; float f; } c;
  c.i = ((unsigned int)(unsigned short)u) << 16;
  return c.f;
}
__device__ __forceinline__ short f2bf(float f) {
  union { float f; unsigned int i; } c; c.f = f;
  unsigned int x = c.i;
  x += 0x7fffu + ((x >> 16) & 1u);   // round-to-nearest-even
  return (short)(x >> 16);
}

// ---------------- conversion kernels ----------------
__global__ __launch_bounds__(256) void k_cvt_f(const float* __restrict__ f,
                                               short* __restrict__ fbf, int n8) {
  int i = blockIdx.x * 256 + threadIdx.x;
  if (i >= n8) return;
  const floatx4* p = (const floatx4*)(f + (size_t)i * 8);
  floatx4 a = p[0], b = p[1];
  bf16x8 o;
  o[0] = f2bf(a[0]); o[1] = f2bf(a[1]); o[2] = f2bf(a[2]); o[3] = f2bf(a[3]);
  o[4] = f2bf(b[0]); o[5] = f2bf(b[1]); o[6] = f2bf(b[2]); o[7] = f2bf(b[3]);
  *(bf16x8*)(fbf + (size_t)i * 8) = o;
}

// Wq -> WqT (bf16, [n][k]), Wk -> bf16 straight copy ([a][d])
__global__ __launch_bounds__(256) void k_cvt_w(const float* __restrict__ Wq,
                                               const float* __restrict__ Wk,
                                               short* __restrict__ WqT,
                                               short* __restrict__ Wkb) {
  int o = blockIdx.x * 256 + threadIdx.x;
  if (blockIdx.x < 1024) {
    int n = o >> 9, k = o & 511;
    WqT[(size_t)n * 512 + k] = f2bf(Wq[(size_t)k * 512 + n]);
  } else {
    int o2 = o - 262144;
    Wkb[o2] = f2bf(Wk[o2]);
  }
}

// ---------------- MFMA GEMM (m97-style, 128x128 tile, BK=32, 4 waves) ----------------
__device__ __forceinline__ void gll(const short* g, short* l) {
  __builtin_amdgcn_global_load_lds(
      (const __attribute__((address_space(1))) unsigned int*)(g),
      (__attribute__((address_space(3))) unsigned int*)(l), 16, 0, 0);
}

// C[row][ocoff+col] = sum_k A[row][koff+k] * BT[col][koff+k]  (+ bias[col] if bias)
// koff = z*z_koff ; ocoff = z*z_coff
__global__ __launch_bounds__(256) void k_gemm(
    const short* __restrict__ A, int lda,
    const short* __restrict__ BT, int ldb,
    short* __restrict__ O, int ldo,
    const float* __restrict__ bias, int K, int z_koff, int z_coff) {
  __shared__ __align__(16) short As[2][4096];
  __shared__ __align__(16) short Bs[2][4096];

  const int tid = threadIdx.x;
  const int lane = tid & 63;
  const int wid = tid >> 6;
  const int wr = wid >> 1, wc = wid & 1;
  const int row0 = blockIdx.y * 128;
  const int col0 = blockIdx.x * 128;
  const int z = blockIdx.z;
  const int koff = z * z_koff;
  const int ocoff = z * z_coff;

  const int r1 = tid >> 2, hk = tid & 3;   // staging: unit u=tid -> row r1, 16B chunk hk
  const short* Ag1 = A + (size_t)(row0 + r1) * lda + koff + hk * 8;
  const short* Ag2 = A + (size_t)(row0 + 64 + r1) * lda + koff + hk * 8;
  const short* Bg1 = BT + (size_t)(col0 + r1) * ldb + koff + hk * 8;
  const short* Bg2 = BT + (size_t)(col0 + 64 + r1) * ldb + koff + hk * 8;

  floatx4 acc[4][4];
  const floatx4 zero = {0.0f, 0.0f, 0.0f, 0.0f};
#pragma unroll
  for (int m = 0; m < 4; ++m)
#pragma unroll
    for (int n = 0; n < 4; ++n) acc[m][n] = zero;

  const int NT = K >> 5;
  int cur = 0;

  auto stage = [&](int q, int kb) {
    gll(Ag1 + kb, &As[q][tid * 8]);
    gll(Ag2 + kb, &As[q][tid * 8 + 2048]);
    gll(Bg1 + kb, &Bs[q][tid * 8]);
    gll(Bg2 + kb, &Bs[q][tid * 8 + 2048]);
  };

  stage(0, 0);
  __syncthreads();

  for (int t = 0; t < NT; ++t) {
    if (t + 1 < NT) stage(cur ^ 1, (t + 1) * 32);
    bf16x8 af[4], bfr[4];
#pragma unroll
    for (int m = 0; m < 4; ++m)
      af[m] = *(const bf16x8*)&As[cur][(wr * 64 + m * 16 + (lane & 15)) * 32 + (lane >> 4) * 8];
#pragma unroll
    for (int n = 0; n < 4; ++n)
      bfr[n] = *(const bf16x8*)&Bs[cur][(wc * 64 + n * 16 + (lane & 15)) * 32 + (lane >> 4) * 8];
#pragma unroll
    for (int m = 0; m < 4; ++m)
#pragma unroll
      for (int n = 0; n < 4; ++n)
        acc[m][n] = __builtin_amdgcn_mfma_f32_16x16x32_bf16(af[m], bfr[n], acc[m][n], 0, 0, 0);
    __syncthreads();
    cur ^= 1;
  }

  // epilogue: C/D layout col=lane&15, row=(lane>>4)*4+j
#pragma unroll
  for (int m = 0; m < 4; ++m) {
    int rowb = row0 + wr * 64 + m * 16 + (lane >> 4) * 4;
#pragma unroll
    for (int n = 0; n < 4; ++n) {
      int lcol = col0 + wc * 64 + n * 16 + (lane & 15);
      float bv = bias ? bias[lcol] : 0.0f;
      int ocol = ocoff + lcol;
#pragma unroll
      for (int j = 0; j < 4; ++j) {
        O[(size_t)(rowb + j) * ldo + ocol] = f2bf(acc[m][n][j] + bv);
      }
    }
  }
}

// ---------------- stats + attention fusion (one wave per row b) ----------------
__global__ __launch_bounds__(256) void k_stats(
    const float* __restrict__ f, const float* __restrict__ sf,
    const float* __restrict__ emb, const short* __restrict__ Qbf,
    const short* __restrict__ Rbf, const float* __restrict__ bk,
    const float* __restrict__ temp, const float* __restrict__ attn_w,
    float* __restrict__ comb_out) {
  const int lane = threadIdx.x & 63;
  const int wid = threadIdx.x >> 6;
  const int b = blockIdx.x * 4 + wid;
  const int a0 = lane * 8;

  const floatx4* fp = (const floatx4*)(f + (size_t)b * D_N + a0);
  floatx4 fA = fp[0], fB = fp[1];
  float fv[8];
#pragma unroll
  for (int j = 0; j < 4; ++j) { fv[j] = fA[j]; fv[4 + j] = fB[j]; }
  float ffp = 0;
#pragma unroll
  for (int j = 0; j < 8; ++j) ffp += fv[j] * fv[j];

  bf16x8 qv = *(const bf16x8*)(Qbf + (size_t)b * D_N + a0);
  float qbkp = 0;
#pragma unroll
  for (int j = 0; j < 8; ++j) qbkp += bf2f(qv[j]) * bk[a0 + j];

  float rf[H_N][8];
#pragma unroll
  for (int h = 0; h < H_N; ++h) {
    bf16x8 rv = *(const bf16x8*)(Rbf + (size_t)b * 2048 + h * 512 + a0);
#pragma unroll
    for (int j = 0; j < 8; ++j) rf[h][j] = bf2f(rv[j]);
  }

  const int myh = lane >> 4;   // lane's 8 elems lie entirely inside head (a0>>7)
  float fs_[S_N], ss_[S_N], sc_[S_N][H_N];

#pragma unroll
  for (int s = 0; s < S_N; ++s) {
    const floatx4* sp = (const floatx4*)(sf + ((size_t)s * B_N + b) * D_N + a0);
    floatx4 sA = sp[0], sB = sp[1];
    const floatx4* ep = (const floatx4*)(emb + (size_t)s * D_N + a0);
    floatx4 eA = ep[0], eB = ep[1];
    float sv[8], se[8];
#pragma unroll
    for (int j = 0; j < 4; ++j) {
      sv[j] = sA[j]; sv[4 + j] = sB[j];
      se[j] = sA[j] + eA[j]; se[4 + j] = sB[j] + eB[j];
    }
    float fsp = 0, ssp = 0;
    float scp[H_N];
#pragma unroll
    for (int h = 0; h < H_N; ++h) scp[h] = (myh == h) ? qbkp : 0.0f;
#pragma unroll
    for (int j = 0; j < 8; ++j) {
      fsp += fv[j] * sv[j];
      ssp += sv[j] * sv[j];
#pragma unroll
      for (int h = 0; h < H_N; ++h) scp[h] += se[j] * rf[h][j];
    }
#pragma unroll
    for (int o = 1; o < 64; o <<= 1) {
      fsp += __shfl_xor(fsp, o, 64);
      ssp += __shfl_xor(ssp, o, 64);
#pragma unroll
      for (int h = 0; h < H_N; ++h) scp[h] += __shfl_xor(scp[h], o, 64);
    }
    fs_[s] = fsp; ss_[s] = ssp;
#pragma unroll
    for (int h = 0; h < H_N; ++h) sc_[s][h] = scp[h];
  }
  float ffv = ffp;
#pragma unroll
  for (int o = 1; o < 64; o <<= 1) ffv += __shfl_xor(ffv, o, 64);

  // ---- finalize (all lanes redundantly, wave-uniform) ----
  const float t = fabsf(temp[0]);

  // MHA: softmax over s per head of scores/(sqrt(hd)*t), mean over heads
  float amha[S_N] = {0, 0, 0, 0, 0};
  const float inv_mha = 1.0f / (sqrtf(128.0f) * t);
#pragma unroll
  for (int h = 0; h < H_N; ++h) {
    float lg[S_N];
#pragma unroll
    for (int s = 0; s < S_N; ++s) lg[s] = sc_[s][h] * inv_mha;
    float mx = lg[0];
#pragma unroll
    for (int s = 1; s < S_N; ++s) mx = fmaxf(mx, lg[s]);
    float e[S_N], sum = 0;
#pragma unroll
    for (int s = 0; s < S_N; ++s) { e[s] = __expf(lg[s] - mx); sum += e[s]; }
    float isum = 0.25f / sum;
#pragma unroll
    for (int s = 0; s < S_N; ++s) amha[s] += e[s] * isum;
  }

  // geometric
  float ageo[S_N];
  {
    const float nf = fmaxf(sqrtf(ffv), 1e-12f);
    float g[S_N];
#pragma unroll
    for (int s = 0; s < S_N; ++s) {
      float ns = fmaxf(sqrtf(ss_[s]), 1e-12f);
      float cs0 = fs_[s] / (nf * ns);
      cs0 = fminf(fmaxf(cs0, -1.0f + 1e-7f), 1.0f - 1e-7f);
      g[s] = __expf(-acosf(cs0) / t);
    }
    float mx = g[0];
#pragma unroll
    for (int s = 1; s < S_N; ++s) mx = fmaxf(mx, g[s]);
    float sum = 0;
#pragma unroll
    for (int s = 0; s < S_N; ++s) { ageo[s] = __expf(g[s] - mx); sum += ageo[s]; }
#pragma unroll
    for (int s = 0; s < S_N; ++s) ageo[s] /= sum;
  }

  // Cayley-Menger proxy: vol = Aff*ff + Ass*ss + Afs*fs  (closed form of 25-pair mean)
  float acay[S_N];
  {
    const float SQ2 = 1.41421356237309515f;
    const float Aff = 0.72f;
    const float Ass = 0.72f - 0.32f * SQ2;
    const float Afs = -(8.0f + 4.0f * SQ2) / 25.0f;
    float lg[S_N];
#pragma unroll
    for (int s = 0; s < S_N; ++s)
      lg[s] = (Aff * ffv + Ass * ss_[s] + Afs * fs_[s]) / t;
    float mx = lg[0];
#pragma unroll
    for (int s = 1; s < S_N; ++s) mx = fmaxf(mx, lg[s]);
    float sum = 0;
#pragma unroll
    for (int s = 0; s < S_N; ++s) { acay[s] = __expf(lg[s] - mx); sum += acay[s]; }
#pragma unroll
    for (int s = 0; s < S_N; ++s) acay[s] /= sum;
  }

  // fuse
  float w0 = attn_w[0], w1 = attn_w[1], w2 = attn_w[2];
  float wm = fmaxf(w0, fmaxf(w1, w2));
  float e0 = __expf(w0 - wm), e1 = __expf(w1 - wm), e2 = __expf(w2 - wm);
  float wsum = e0 + e1 + e2;
  w0 = e0 / wsum; w1 = e1 / wsum; w2 = e2 / wsum;

  float cb[S_N], csum = 0;
#pragma unroll
  for (int s = 0; s < S_N; ++s) {
    cb[s] = w0 * amha[s] + w1 * ageo[s] + w2 * acay[s];
    csum += cb[s];
  }
  float ic = 1.0f / csum;
  if (lane == 0) {
#pragma unroll
    for (int s = 0; s < S_N; ++s) comb_out[(size_t)b * S_N + s] = cb[s] * ic;
  }
}

// ---------------- final logits mix: out[b,c] = sum_s comb[b,s]*logits[s,b,c] ----------------
__global__ __launch_bounds__(256) void k_mix(const float* __restrict__ logits,
                                             const float* __restrict__ comb,
                                             float* __restrict__ out) {
  const int b = blockIdx.x;
  const int c0 = threadIdx.x * 8;
  float cs[S_N];
#pragma unroll
  for (int s = 0; s < S_N; ++s) cs[s] = comb[(size_t)b * S_N + s];
  floatx4 accA = {0, 0, 0, 0}, accB = {0, 0, 0, 0};
#pragma unroll
  for (int s = 0; s < S_N; ++s) {
    const float* lp = logits + ((size_t)s * B_N + b) * C_N + c0;
    floatx4 lA = *(const floatx4*)lp;
    floatx4 lB = *(const floatx4*)(lp + 4);
    accA += lA * cs[s];
    accB += lB * cs[s];
  }
  float* op = out + (size_t)b * C_N + c0;
  *(floatx4*)op = accA;
  *(floatx4*)(op + 4) = accB;
}

extern "C" void kernel_launch(void* const* d_in, const int* in_sizes, int n_in,
                              void* d_out, int out_size, void* d_ws, size_t ws_size,
                              hipStream_t stream) {
  const float* features = (const float*)d_in[0];
  const float* logits   = (const float*)d_in[1];
  const float* sf       = (const float*)d_in[2];
  const float* Wq       = (const float*)d_in[3];
  const float* bq       = (const float*)d_in[4];
  const float* Wk       = (const float*)d_in[5];
  const float* bk       = (const float*)d_in[6];
  const float* emb      = (const float*)d_in[9];
  const float* temp     = (const float*)d_in[10];
  const float* attn_w   = (const float*)d_in[11];

  float* out  = (float*)d_out;
  float* comb = out + (size_t)B_N * C_N;

  char* w = (char*)d_ws;
  short* fbf = (short*)(w);                    // 8192*512  bf16 =  8.39 MB
  short* Qbf = (short*)(w + 8388608);          // 8192*512  bf16 =  8.39 MB
  short* Rbf = (short*)(w + 16777216);         // 8192*2048 bf16 = 33.55 MB
  short* WqT = (short*)(w + 50331648);         // 512*512   bf16 =  0.52 MB
  short* Wkb = (short*)(w + 50855936);         // 512*512   bf16 =  0.52 MB

  // 1. convert features to bf16
  k_cvt_f<<<dim3(2048), dim3(256), 0, stream>>>(features, fbf, 524288);
  // 2. convert/transpose weights
  k_cvt_w<<<dim3(2048), dim3(256), 0, stream>>>(Wq, Wk, WqT, Wkb);
  // 3. Q = f @ Wq + bq   [8192,512] bf16
  k_gemm<<<dim3(4, 64, 1), dim3(256), 0, stream>>>(fbf, 512, WqT, 512, Qbf, 512,
                                                   bq, 512, 0, 0);
  // 4. R[b, h*512+a] = sum_j Q[b,h*128+j] * Wk[a,h*128+j]   (grid.z = head)
  k_gemm<<<dim3(4, 64, 4), dim3(256), 0, stream>>>(Qbf, 512, Wkb, 512, Rbf, 2048,
                                                   (const float*)nullptr, 128, 128, 512);
  // 5. per-row stats + three attentions + fuse -> combined  (also writes d_out tail)
  k_stats<<<dim3(2048), dim3(256), 0, stream>>>(features, sf, emb, Qbf, Rbf, bk,
                                                temp, attn_w, comb);
  // 6. out[b,c] = sum_s combined[b,s] * logits[s,b,c]
  k_mix<<<dim3(8192), dim3(256), 0, stream>>>(logits, comb, out);
}

// Round 2
// 157.212 us; speedup vs baseline: 1.0079x; 1.0079x over previous
//
#include <hip/hip_runtime.h>
#include <math.h>

#define B_N 8192
#define D_N 512
#define S_N 5
#define C_N 2048
#define H_N 4
#define RB 32          // rows per mega block

typedef __attribute__((ext_vector_type(8))) short bf16x8;
typedef __attribute__((ext_vector_type(4))) float floatx4;

__device__ __forceinline__ float bf2f(short u) {
  union { unsigned int i; float f; } c;
  c.i = ((unsigned int)(unsigned short)u) << 16;
  return c.f;
}
__device__ __forceinline__ short f2bf(float f) {
  union { float f; unsigned int i; } c; c.f = f;
  unsigned int x = c.i;
  x += 0x7fffu + ((x >> 16) & 1u);   // round-to-nearest-even
  return (short)(x >> 16);
}
__device__ __forceinline__ unsigned long long pack4(float a, float b, float c, float d) {
  return (unsigned long long)(unsigned short)f2bf(a)
       | ((unsigned long long)(unsigned short)f2bf(b) << 16)
       | ((unsigned long long)(unsigned short)f2bf(c) << 32)
       | ((unsigned long long)(unsigned short)f2bf(d) << 48);
}

// ---------------- weight prep: Wq -> WqT bf16 [n][k], Wk -> bf16 [a][d] ----------------
__global__ __launch_bounds__(256) void k_prep(const float* __restrict__ Wq,
                                              const float* __restrict__ Wk,
                                              short* __restrict__ WqT,
                                              short* __restrict__ Wkb) {
  int o = blockIdx.x * 256 + threadIdx.x;
  if (blockIdx.x < 1024) {
    int n = o >> 9, k = o & 511;
    WqT[(size_t)n * 512 + k] = f2bf(Wq[(size_t)k * 512 + n]);
  } else {
    int o2 = o - 262144;
    Wkb[o2] = f2bf(Wk[o2]);
  }
}

// ---------------- mega: cvt + Q-GEMM + R-GEMM + scores + stats + 3 softmaxes ----------------
// grid 256 blocks x 32 rows, 256 threads (4 waves; wave w == head w)
__global__ __launch_bounds__(256, 2) void k_mega(
    const float* __restrict__ f, const float* __restrict__ sf,
    const float* __restrict__ emb, const short* __restrict__ WqT,
    const short* __restrict__ Wkb, const float* __restrict__ bq,
    const float* __restrict__ bk, const float* __restrict__ temp,
    const float* __restrict__ attn_w, float* __restrict__ comb_out) {
  // uni: phase 0/1 = Abf (32KB, swizzled [32][512] bf16); phase 2 = sfe [5][32][132] bf16
  __shared__ __align__(16) short uni[21120];      // 42240 B
  __shared__ __align__(16) short Qbf[16384];      // 32 KB swizzled [32][512] bf16
  __shared__ float ffLds[RB];
  __shared__ float qtLds[RB][H_N];
  __shared__ float scLds[RB][H_N][S_N];
  __shared__ float fsLds[S_N][RB];
  __shared__ float ssLds[S_N][RB];

  const int tid = threadIdx.x;
  const int lane = tid & 63;
  const int wid = tid >> 6;
  const int b0 = blockIdx.x * RB;

  // ================= phase 0: f -> Abf (bf16, swizzled) + ff =================
  {
    const int r0 = tid >> 3;
    const int c0 = (tid & 7) * 64;
    const float* fp = f + (size_t)(b0 + r0) * D_N + c0;
    float ffp = 0.0f;
#pragma unroll
    for (int i = 0; i < 8; ++i) {   // 8 bf16x8 chunks of 8 floats
      floatx4 a = *(const floatx4*)(fp + i * 8);
      floatx4 b = *(const floatx4*)(fp + i * 8 + 4);
      ffp += a[0]*a[0] + a[1]*a[1] + a[2]*a[2] + a[3]*a[3];
      ffp += b[0]*b[0] + b[1]*b[1] + b[2]*b[2] + b[3]*b[3];
      bf16x8 o;
      o[0]=f2bf(a[0]); o[1]=f2bf(a[1]); o[2]=f2bf(a[2]); o[3]=f2bf(a[3]);
      o[4]=f2bf(b[0]); o[5]=f2bf(b[1]); o[6]=f2bf(b[2]); o[7]=f2bf(b[3]);
      int byteoff = (r0 * 1024 + (c0 + i * 8) * 2) ^ ((r0 & 7) << 4);
      *(bf16x8*)((char*)uni + byteoff) = o;
    }
    ffp += __shfl_xor(ffp, 1, 64);
    ffp += __shfl_xor(ffp, 2, 64);
    ffp += __shfl_xor(ffp, 4, 64);
    if ((tid & 7) == 0) ffLds[r0] = ffp;
  }
  __syncthreads();

  // ================= phase 1: Q = Abf @ WqT (+bq); q~ = Q.bk; Qbf LDS =================
  {
    const int wcol0 = wid * 128;     // wave's 128-col strip == head wid
    floatx4 acc[2][8];
    const floatx4 zero = {0.f, 0.f, 0.f, 0.f};
#pragma unroll
    for (int m = 0; m < 2; ++m)
#pragma unroll
      for (int n = 0; n < 8; ++n) acc[m][n] = zero;

    for (int ks = 0; ks < 16; ++ks) {
      bf16x8 bfr[8];
#pragma unroll
      for (int n = 0; n < 8; ++n) {
        int col = wcol0 + n * 16 + (lane & 15);
        bfr[n] = *(const bf16x8*)(WqT + (size_t)col * 512 + ks * 32 + (lane >> 4) * 8);
      }
      bf16x8 afr[2];
#pragma unroll
      for (int m = 0; m < 2; ++m) {
        int row = m * 16 + (lane & 15);
        int byteoff = (row * 1024 + (ks * 32 + (lane >> 4) * 8) * 2) ^ ((row & 7) << 4);
        afr[m] = *(const bf16x8*)((const char*)uni + byteoff);
      }
#pragma unroll
      for (int m = 0; m < 2; ++m)
#pragma unroll
        for (int n = 0; n < 8; ++n)
          acc[m][n] = __builtin_amdgcn_mfma_f32_16x16x32_bf16(afr[m], bfr[n], acc[m][n], 0, 0, 0);
    }

    float bqv[8], bkv[8];
#pragma unroll
    for (int n = 0; n < 8; ++n) {
      int col = wcol0 + n * 16 + (lane & 15);
      bqv[n] = bq[col];
      bkv[n] = bk[col];
    }
    // write Q (bf16, swizzled) and q~ partials
#pragma unroll
    for (int m = 0; m < 2; ++m) {
#pragma unroll
      for (int j = 0; j < 4; ++j) {
        int row = m * 16 + (lane >> 4) * 4 + j;
        float qp = 0.0f;
#pragma unroll
        for (int n = 0; n < 8; ++n) {
          float qv = acc[m][n][j] + bqv[n];
          int col = wcol0 + n * 16 + (lane & 15);
          int byteoff = (row * 1024 + col * 2) ^ ((row & 7) << 4);
          *(short*)((char*)Qbf + byteoff) = f2bf(qv);
          qp += qv * bkv[n];
        }
        qp += __shfl_xor(qp, 1, 64);
        qp += __shfl_xor(qp, 2, 64);
        qp += __shfl_xor(qp, 4, 64);
        qp += __shfl_xor(qp, 8, 64);
        if ((lane & 15) == 0) qtLds[row][wid] = qp;
      }
    }
  }
  __syncthreads();

  // ================= phase 2: per 128-col chunk: stage sfe + stats; R-MFMA + consume =====
  float scp[S_N][2][4];   // score partials, persist across chunks
#pragma unroll
  for (int s = 0; s < S_N; ++s)
#pragma unroll
    for (int m = 0; m < 2; ++m)
#pragma unroll
      for (int j = 0; j < 4; ++j) scp[s][m][j] = 0.0f;
  float ssp[S_N] = {0, 0, 0, 0, 0}, fsp[S_N] = {0, 0, 0, 0, 0};

  const int h = wid;
  for (int cc = 0; cc < 4; ++cc) {
    // ---- 2a: stage sfe chunk (bf16 LDS, 264B-pad rows) + ss/fs partials (f32) ----
    {
      const int r1 = tid >> 3;
      const int cs0 = (tid & 7) * 16;          // col within chunk
      const int ac0 = cc * 128 + cs0;          // global col
      const float* fpp = f + (size_t)(b0 + r1) * D_N + ac0;
      float fsl[16];
#pragma unroll
      for (int i = 0; i < 4; ++i) {
        floatx4 v = *(const floatx4*)(fpp + i * 4);
        fsl[i * 4 + 0] = v[0]; fsl[i * 4 + 1] = v[1];
        fsl[i * 4 + 2] = v[2]; fsl[i * 4 + 3] = v[3];
      }
#pragma unroll
      for (int s = 0; s < S_N; ++s) {
        const float* sp = sf + ((size_t)s * B_N + b0 + r1) * D_N + ac0;
        const float* ep = emb + s * D_N + ac0;
        float sv[16], se[16];
#pragma unroll
        for (int i = 0; i < 4; ++i) {
          floatx4 a = *(const floatx4*)(sp + i * 4);
          floatx4 e = *(const floatx4*)(ep + i * 4);
#pragma unroll
          for (int q = 0; q < 4; ++q) {
            sv[i * 4 + q] = a[q];
            se[i * 4 + q] = a[q] + e[q];
          }
        }
        float ssl = 0.0f, fsll = 0.0f;
#pragma unroll
        for (int q = 0; q < 16; ++q) { ssl += sv[q] * sv[q]; fsll += fsl[q] * sv[q]; }
        ssp[s] += ssl; fsp[s] += fsll;
        int rowbase = (s * RB + r1) * 264 + cs0 * 2;
#pragma unroll
        for (int q = 0; q < 4; ++q) {
          unsigned long long pk = pack4(se[q*4], se[q*4+1], se[q*4+2], se[q*4+3]);
          *(unsigned long long*)((char*)uni + rowbase + q * 8) = pk;
        }
      }
    }
    __syncthreads();

    // ---- 2b: R chunk = Qbf(head h) @ Wkb^T, consume with sfe ----
    {
      floatx4 acc2[2][8];
      const floatx4 zero = {0.f, 0.f, 0.f, 0.f};
#pragma unroll
      for (int m = 0; m < 2; ++m)
#pragma unroll
        for (int n = 0; n < 8; ++n) acc2[m][n] = zero;

#pragma unroll
      for (int ks = 0; ks < 4; ++ks) {
        bf16x8 bfr[8];
#pragma unroll
        for (int n = 0; n < 8; ++n) {
          int a = cc * 128 + n * 16 + (lane & 15);
          bfr[n] = *(const bf16x8*)(Wkb + (size_t)a * 512 + h * 128 + ks * 32 + (lane >> 4) * 8);
        }
        bf16x8 afr[2];
#pragma unroll
        for (int m = 0; m < 2; ++m) {
          int row = m * 16 + (lane & 15);
          int byteoff = (row * 1024 + (h * 128 + ks * 32 + (lane >> 4) * 8) * 2) ^ ((row & 7) << 4);
          afr[m] = *(const bf16x8*)((const char*)Qbf + byteoff);
        }
#pragma unroll
        for (int m = 0; m < 2; ++m)
#pragma unroll
          for (int n = 0; n < 8; ++n)
            acc2[m][n] = __builtin_amdgcn_mfma_f32_16x16x32_bf16(afr[m], bfr[n], acc2[m][n], 0, 0, 0);
      }
      // consume: scp[s][m][j] += sum_n R[row][16n+l15] * sfe[s][row][16n+l15]
#pragma unroll
      for (int s = 0; s < S_N; ++s) {
#pragma unroll
        for (int m = 0; m < 2; ++m) {
#pragma unroll
          for (int j = 0; j < 4; ++j) {
            int row = m * 16 + (lane >> 4) * 4 + j;
            int base = (s * RB + row) * 264 + (lane & 15) * 2;
            float p = 0.0f;
#pragma unroll
            for (int n = 0; n < 8; ++n) {
              short sv = *(const short*)((const char*)uni + base + n * 32);
              p += acc2[m][n][j] * bf2f(sv);
            }
            scp[s][m][j] += p;
          }
        }
      }
    }
    __syncthreads();
  }

  // ================= phase 3: reductions + finalize =================
#pragma unroll
  for (int s = 0; s < S_N; ++s)
#pragma unroll
    for (int m = 0; m < 2; ++m)
#pragma unroll
      for (int j = 0; j < 4; ++j) {
        float v = scp[s][m][j];
        v += __shfl_xor(v, 1, 64);
        v += __shfl_xor(v, 2, 64);
        v += __shfl_xor(v, 4, 64);
        v += __shfl_xor(v, 8, 64);
        if ((lane & 15) == 0) scLds[m * 16 + (lane >> 4) * 4 + j][wid][s] = v;
      }
  {
    const int r1 = tid >> 3;
#pragma unroll
    for (int s = 0; s < S_N; ++s) {
      float u = ssp[s], v = fsp[s];
      u += __shfl_xor(u, 1, 64); v += __shfl_xor(v, 1, 64);
      u += __shfl_xor(u, 2, 64); v += __shfl_xor(v, 2, 64);
      u += __shfl_xor(u, 4, 64); v += __shfl_xor(v, 4, 64);
      if ((tid & 7) == 0) { ssLds[s][r1] = u; fsLds[s][r1] = v; }
    }
  }
  __syncthreads();

  if (tid < RB) {
    const int r = tid;
    const float ffv = ffLds[r];
    const float t = fabsf(temp[0]);

    float amha[S_N] = {0, 0, 0, 0, 0};
    const float inv_mha = 1.0f / (sqrtf(128.0f) * t);
#pragma unroll
    for (int hh = 0; hh < H_N; ++hh) {
      float lg[S_N];
#pragma unroll
      for (int s = 0; s < S_N; ++s) lg[s] = (scLds[r][hh][s] + qtLds[r][hh]) * inv_mha;
      float mx = lg[0];
#pragma unroll
      for (int s = 1; s < S_N; ++s) mx = fmaxf(mx, lg[s]);
      float e[S_N], sum = 0;
#pragma unroll
      for (int s = 0; s < S_N; ++s) { e[s] = __expf(lg[s] - mx); sum += e[s]; }
      float isum = 0.25f / sum;
#pragma unroll
      for (int s = 0; s < S_N; ++s) amha[s] += e[s] * isum;
    }

    float ageo[S_N];
    {
      const float nf = fmaxf(sqrtf(ffv), 1e-12f);
      float g[S_N];
#pragma unroll
      for (int s = 0; s < S_N; ++s) {
        float ns = fmaxf(sqrtf(ssLds[s][r]), 1e-12f);
        float cs0 = fsLds[s][r] / (nf * ns);
        cs0 = fminf(fmaxf(cs0, -1.0f + 1e-7f), 1.0f - 1e-7f);
        g[s] = __expf(-acosf(cs0) / t);
      }
      float mx = g[0];
#pragma unroll
      for (int s = 1; s < S_N; ++s) mx = fmaxf(mx, g[s]);
      float sum = 0;
#pragma unroll
      for (int s = 0; s < S_N; ++s) { ageo[s] = __expf(g[s] - mx); sum += ageo[s]; }
#pragma unroll
      for (int s = 0; s < S_N; ++s) ageo[s] /= sum;
    }

    float acay[S_N];
    {
      const float SQ2 = 1.41421356237309515f;
      const float Aff = 0.72f;
      const float Ass = 0.72f - 0.32f * SQ2;
      const float Afs = -(8.0f + 4.0f * SQ2) / 25.0f;
      float lg[S_N];
#pragma unroll
      for (int s = 0; s < S_N; ++s)
        lg[s] = (Aff * ffv + Ass * ssLds[s][r] + Afs * fsLds[s][r]) / t;
      float mx = lg[0];
#pragma unroll
      for (int s = 1; s < S_N; ++s) mx = fmaxf(mx, lg[s]);
      float sum = 0;
#pragma unroll
      for (int s = 0; s < S_N; ++s) { acay[s] = __expf(lg[s] - mx); sum += acay[s]; }
#pragma unroll
      for (int s = 0; s < S_N; ++s) acay[s] /= sum;
    }

    float w0 = attn_w[0], w1 = attn_w[1], w2 = attn_w[2];
    float wm = fmaxf(w0, fmaxf(w1, w2));
    float e0 = __expf(w0 - wm), e1 = __expf(w1 - wm), e2 = __expf(w2 - wm);
    float wsum = e0 + e1 + e2;
    w0 = e0 / wsum; w1 = e1 / wsum; w2 = e2 / wsum;

    float cb[S_N], csum = 0;
#pragma unroll
    for (int s = 0; s < S_N; ++s) {
      cb[s] = w0 * amha[s] + w1 * ageo[s] + w2 * acay[s];
      csum += cb[s];
    }
    float ic = 1.0f / csum;
#pragma unroll
    for (int s = 0; s < S_N; ++s) comb_out[(size_t)(b0 + r) * S_N + s] = cb[s] * ic;
  }
}

// ---------------- final logits mix: out[b,c] = sum_s comb[b,s]*logits[s,b,c] ----------------
__global__ __launch_bounds__(256) void k_mix(const float* __restrict__ logits,
                                             const float* __restrict__ comb,
                                             float* __restrict__ out) {
  const int b = blockIdx.x;
  const int c0 = threadIdx.x * 8;
  float cs[S_N];
#pragma unroll
  for (int s = 0; s < S_N; ++s) cs[s] = comb[(size_t)b * S_N + s];
  floatx4 accA = {0, 0, 0, 0}, accB = {0, 0, 0, 0};
#pragma unroll
  for (int s = 0; s < S_N; ++s) {
    const float* lp = logits + ((size_t)s * B_N + b) * C_N + c0;
    floatx4 lA = *(const floatx4*)lp;
    floatx4 lB = *(const floatx4*)(lp + 4);
    accA += lA * cs[s];
    accB += lB * cs[s];
  }
  float* op = out + (size_t)b * C_N + c0;
  *(floatx4*)op = accA;
  *(floatx4*)(op + 4) = accB;
}

extern "C" void kernel_launch(void* const* d_in, const int* in_sizes, int n_in,
                              void* d_out, int out_size, void* d_ws, size_t ws_size,
                              hipStream_t stream) {
  const float* features = (const float*)d_in[0];
  const float* logits   = (const float*)d_in[1];
  const float* sf       = (const float*)d_in[2];
  const float* Wq       = (const float*)d_in[3];
  const float* bq       = (const float*)d_in[4];
  const float* Wk       = (const float*)d_in[6 - 1];  // d_in[5] = Wk
  const float* bk       = (const float*)d_in[6];
  const float* emb      = (const float*)d_in[9];
  const float* temp     = (const float*)d_in[10];
  const float* attn_w   = (const float*)d_in[11];

  float* out  = (float*)d_out;
  float* comb = out + (size_t)B_N * C_N;

  char* w = (char*)d_ws;
  short* WqT = (short*)(w);                    // 512*512 bf16 = 0.52 MB
  short* Wkb = (short*)(w + 524288);           // 512*512 bf16 = 0.52 MB

  // 1. weights -> bf16 (WqT transposed)
  k_prep<<<dim3(2048), dim3(256), 0, stream>>>(Wq, Wk, WqT, Wkb);
  // 2. fused cvt + Q-GEMM + R-GEMM + scores + stats + softmaxes -> combined
  k_mega<<<dim3(256), dim3(256), 0, stream>>>(features, sf, emb, WqT, Wkb, bq, bk,
                                              temp, attn_w, comb);
  // 3. out[b,c] = sum_s combined[b,s] * logits[s,b,c]
  k_mix<<<dim3(8192), dim3(256), 0, stream>>>(logits, comb, out);
}